// Round 12
// baseline (47.908 us; speedup 1.0000x reference)
//
#include <hip/hip_runtime.h>

#define TOKS 65536
#define ED 64
#define NE 1024
#define CH_STRIDE 4096      // 64*64
#define B_STRIDE 262144     // 64*64*64

typedef __bf16 bf16x8 __attribute__((ext_vector_type(8)));
typedef float f32x16 __attribute__((ext_vector_type(16)));
typedef unsigned short ushort_t;
typedef unsigned int uint_t;

// ws layout:
//   efrag    @ 0      : 32ct x 4ks x 64lane x 8 bf16 (hi of -2*emb) [128 KB]
//   enorm    @ 131072 : 1024 f32 (np-pairwise ||e||^2, exact)        [4 KB]
//   hist     @ 135168 : 1024 i32                                     [4 KB]
//   lossPart @ 143360 : 1024 f64 per-block partial loss              [8 KB]

__device__ __forceinline__ ushort_t f2bf(float x) {
    uint_t u = __float_as_uint(x);
    uint_t r = u + 0x7FFFu + ((u >> 16) & 1u);   // RNE
    return (ushort_t)(r >> 16);
}

// ---- prep E: wave per code. enorm via shfl-replicated numpy pairwise (exact
// op order: 8 accumulators, 7 sequential stride-8 adds, 3-level tree).
__global__ __launch_bounds__(256) void vq_prep_e(const float* __restrict__ emb,
                                                 ushort_t* __restrict__ efrag,
                                                 float* __restrict__ enorm,
                                                 int* __restrict__ hist) {
    const int tid = threadIdx.x;
    const int w = tid >> 6, lane = tid & 63;
    const int j = blockIdx.x * 4 + w;

    const float e = emb[j * 64 + lane];
    const float sq = __fmul_rn(e, e);
    float acc = sq;
    acc = __fadd_rn(acc, __shfl_down(sq, 8, 64));
    acc = __fadd_rn(acc, __shfl_down(sq, 16, 64));
    acc = __fadd_rn(acc, __shfl_down(sq, 24, 64));
    acc = __fadd_rn(acc, __shfl_down(sq, 32, 64));
    acc = __fadd_rn(acc, __shfl_down(sq, 40, 64));
    acc = __fadd_rn(acc, __shfl_down(sq, 48, 64));
    acc = __fadd_rn(acc, __shfl_down(sq, 56, 64));
    float x = __fadd_rn(acc, __shfl_down(acc, 1, 64));
    float y = __fadd_rn(x, __shfl_down(x, 2, 64));
    float zn = __fadd_rn(y, __shfl_down(y, 4, 64));
    if (lane == 0) enorm[j] = zn;

    const ushort_t h = f2bf(-2.0f * e);
    const int ct = j >> 5, m = j & 31;
    const int ks = lane >> 4, kh = (lane >> 3) & 1, i = lane & 7;
    efrag[(size_t)((ct * 4 + ks) * 512) + (m + 32 * kh) * 8 + i] = h;

    if (blockIdx.x < 4) hist[blockIdx.x * 256 + tid] = 0;
}

// ---- fused: MFMA filter (2 token-tiles share each efrag load) + compacted
// exact rescore + gather/hist/loss + zq. Block = 64 tokens, 4 waves = 4
// code-quarters, 1024 blocks. Loss: plain per-block store (NO global atomic).
__global__ __launch_bounds__(256, 4) void vq_main(
    const float* __restrict__ z,
    const ushort_t* __restrict__ efrag,
    const float* __restrict__ enorm,
    const float* __restrict__ emb,
    float* __restrict__ zq,
    float* __restrict__ out_idx,
    int* __restrict__ hist,
    double* __restrict__ lossPart) {
    __shared__ float z_s[64][68];                 // [channel][token 0..63]
    __shared__ uint_t skey[4][2][32][2][2];       // [wave][tile][n][kh][slot]
    __shared__ float s_zn[64];
    __shared__ unsigned long long s_res[64];      // lex-min (d_bits<<10 | j)
    __shared__ uint_t s_cand[256];                // (token<<10) | j
    __shared__ int s_cnt;
    __shared__ double wsum[4];

    const int tid = threadIdx.x;
    const int w = tid >> 6, lane = tid & 63;
    const int t0 = blockIdx.x * 64;
    const int b = t0 >> 12, hw0 = t0 & 4095;
    const float* zbase = z + (size_t)b * B_STRIDE + hw0;

    // stage z tile (64 ch x 64 tok) for rescore/gather
    {
        const int c = tid >> 2, u0 = (tid & 3) * 16;
        const float* src = zbase + (size_t)c * CH_STRIDE + u0;
        float4 f0 = *(const float4*)(src);
        float4 f1 = *(const float4*)(src + 4);
        float4 f2 = *(const float4*)(src + 8);
        float4 f3 = *(const float4*)(src + 12);
        float4* dst = (float4*)&z_s[c][u0];
        dst[0] = f0; dst[1] = f1; dst[2] = f2; dst[3] = f3;
    }
    if (tid < 64) s_res[tid] = 0xFFFFFFFFFFFFFFFFull;
    if (tid == 0) s_cnt = 0;

    const int n = lane & 31, kh = lane >> 5;

    // B-frags from global: tiles A (tok n) and B (tok 32+n)
    bf16x8 zbA[4], zbB[4];
    #pragma unroll
    for (int ks = 0; ks < 4; ++ks) {
        #pragma unroll
        for (int i = 0; i < 8; ++i) {
            const size_t off = (size_t)(ks * 16 + kh * 8 + i) * CH_STRIDE;
            union { ushort_t u; __bf16 bh; } ca, cb;
            ca.u = f2bf(zbase[off + n]);
            cb.u = f2bf(zbase[off + 32 + n]);
            zbA[ks][i] = ca.bh;
            zbB[ks][i] = cb.bh;
        }
    }

    uint_t kA0 = 0xFFFFFFFFu, kA1 = 0xFFFFFFFFu;
    uint_t kB0 = 0xFFFFFFFFu, kB1 = 0xFFFFFFFFu;
    const bf16x8* eg = (const bf16x8*)efrag;

    // prologue: load ct=0 fragments
    bf16x8 ah0 = eg[(size_t)((w * 8) * 4 + 0) * 64 + lane];
    bf16x8 ah1 = eg[(size_t)((w * 8) * 4 + 1) * 64 + lane];
    bf16x8 ah2 = eg[(size_t)((w * 8) * 4 + 2) * 64 + lane];
    bf16x8 ah3 = eg[(size_t)((w * 8) * 4 + 3) * 64 + lane];

    for (int ct = 0; ct < 8; ++ct) {
        const int gct = w * 8 + ct;
        bf16x8 nx0, nx1, nx2, nx3;
        if (ct < 7) {                              // prefetch next ct
            nx0 = eg[(size_t)((gct + 1) * 4 + 0) * 64 + lane];
            nx1 = eg[(size_t)((gct + 1) * 4 + 1) * 64 + lane];
            nx2 = eg[(size_t)((gct + 1) * 4 + 2) * 64 + lane];
            nx3 = eg[(size_t)((gct + 1) * 4 + 3) * 64 + lane];
        }
        const int jb = gct * 32 + 4 * kh;

        f32x16 accA;
        #pragma unroll
        for (int r = 0; r < 16; ++r) accA[r] = 0.25f;
        accA = __builtin_amdgcn_mfma_f32_32x32x16_bf16(ah0, zbA[0], accA, 0, 0, 0);
        accA = __builtin_amdgcn_mfma_f32_32x32x16_bf16(ah1, zbA[1], accA, 0, 0, 0);
        accA = __builtin_amdgcn_mfma_f32_32x32x16_bf16(ah2, zbA[2], accA, 0, 0, 0);
        accA = __builtin_amdgcn_mfma_f32_32x32x16_bf16(ah3, zbA[3], accA, 0, 0, 0);

        f32x16 accB;
        #pragma unroll
        for (int r = 0; r < 16; ++r) accB[r] = 0.25f;
        accB = __builtin_amdgcn_mfma_f32_32x32x16_bf16(ah0, zbB[0], accB, 0, 0, 0);
        accB = __builtin_amdgcn_mfma_f32_32x32x16_bf16(ah1, zbB[1], accB, 0, 0, 0);
        accB = __builtin_amdgcn_mfma_f32_32x32x16_bf16(ah2, zbB[2], accB, 0, 0, 0);
        accB = __builtin_amdgcn_mfma_f32_32x32x16_bf16(ah3, zbB[3], accB, 0, 0, 0);

        // two independent top-2 insertion chains (3 ops/value each)
        #pragma unroll
        for (int r = 0; r < 16; ++r) {
            const uint_t jbits = (uint_t)(jb + (r & 3) + 8 * (r >> 2));
            uint_t keyA = (__float_as_uint(accA[r]) & 0xFFFFFC00u) | jbits;
            uint_t mxA = max(kA0, keyA);
            kA1 = min(kA1, mxA);
            kA0 = min(kA0, keyA);
            uint_t keyB = (__float_as_uint(accB[r]) & 0xFFFFFC00u) | jbits;
            uint_t mxB = max(kB0, keyB);
            kB1 = min(kB1, mxB);
            kB0 = min(kB0, keyB);
        }
        ah0 = nx0; ah1 = nx1; ah2 = nx2; ah3 = nx3;
    }

    skey[w][0][n][kh][0] = kA0; skey[w][0][n][kh][1] = kA1;
    skey[w][1][n][kh][0] = kB0; skey[w][1][n][kh][1] = kB1;
    __syncthreads();

    // ---- threshold + candidate compaction + znorm (4 threads per token)
    const int t_loc = tid >> 2, m = tid & 3;
    const int tile = t_loc >> 5, nn = t_loc & 31;
    {
        uint_t ck[4];
        ck[0] = skey[m][tile][nn][0][0];
        ck[1] = skey[m][tile][nn][0][1];
        ck[2] = skey[m][tile][nn][1][0];
        ck[3] = skey[m][tile][nn][1][1];
        uint_t kmin = min(min(ck[0], ck[1]), min(ck[2], ck[3]));
        kmin = min(kmin, (uint_t)__shfl_xor((int)kmin, 1, 64));
        kmin = min(kmin, (uint_t)__shfl_xor((int)kmin, 2, 64));
        const float thr = __uint_as_float(kmin & 0xFFFFFC00u) + 4.0e-4f;
        #pragma unroll
        for (int s = 0; s < 4; ++s) {
            if (__uint_as_float(ck[s] & 0xFFFFFC00u) <= thr) {
                int pos = atomicAdd(&s_cnt, 1);
                if (pos < 256)
                    s_cand[pos] = ((uint_t)t_loc << 10) | (ck[s] & 1023u);
            }
        }
    }
    {   // znorm: np pairwise, exact op order; thread m owns slices m and m+4
        float a0 = z_s[m][t_loc];
        float ra = __fmul_rn(a0, a0);
        float b0 = z_s[m + 4][t_loc];
        float rb = __fmul_rn(b0, b0);
        #pragma unroll
        for (int i = 1; i < 8; ++i) {
            float av = z_s[m + 8 * i][t_loc];
            ra = __fadd_rn(ra, __fmul_rn(av, av));
            float bv = z_s[m + 4 + 8 * i][t_loc];
            rb = __fadd_rn(rb, __fmul_rn(bv, bv));
        }
        float xa = __fadd_rn(ra, __shfl_xor(ra, 1, 64));
        float A = __fadd_rn(xa, __shfl_xor(xa, 2, 64));
        float xb = __fadd_rn(rb, __shfl_xor(rb, 1, 64));
        float B = __fadd_rn(xb, __shfl_xor(xb, 2, 64));
        if (m == 0) s_zn[t_loc] = __fadd_rn(A, B);
    }
    __syncthreads();

    // ---- compacted exact rescore: one candidate per thread
    {
        const int cnt = s_cnt;
        if (tid < cnt && tid < 256) {
            const uint_t cd = s_cand[tid];
            const int tok = (int)(cd >> 10), j = (int)(cd & 1023u);
            const float* e = emb + (size_t)j * 64;
            float a0 = 0.f;
            #pragma unroll
            for (int k4 = 0; k4 < 64; k4 += 4) {
                float4 e4 = *(const float4*)(e + k4);
                a0 = __fmaf_rn(z_s[k4 + 0][tok], e4.x, a0);
                a0 = __fmaf_rn(z_s[k4 + 1][tok], e4.y, a0);
                a0 = __fmaf_rn(z_s[k4 + 2][tok], e4.z, a0);
                a0 = __fmaf_rn(z_s[k4 + 3][tok], e4.w, a0);
            }
            float d = __fsub_rn(__fadd_rn(s_zn[tok], enorm[j]), 2.0f * a0);
            unsigned long long key =
                ((unsigned long long)__float_as_uint(d) << 10)
                | (unsigned long long)j;
            atomicMin(&s_res[tok], key);
        }
    }
    __syncthreads();

    // ---- gather + loss (4 threads/token, interleaved channels) + outputs
    const int bj = (int)(s_res[t_loc] & 1023u);
    if (m == 0) {
        out_idx[t0 + t_loc] = (float)bj;
        atomicAdd(&hist[bj], 1);
    }
    double ls = 0.0;
    {
        const float* e = emb + (size_t)bj * 64;
        #pragma unroll
        for (int i = 0; i < 16; ++i) {
            const int k = m + 4 * i;
            float ev = e[k];
            float zv = z_s[k][t_loc];
            z_s[k][t_loc] = ev;                    // tile becomes z_q
            float df = ev - zv;
            ls += (double)(df * df);
        }
    }
    #pragma unroll
    for (int off = 32; off > 0; off >>= 1) ls += __shfl_down(ls, off, 64);
    if (lane == 0) wsum[w] = ls;
    __syncthreads();                               // z_s fully z_q; wsum ready
    if (tid == 0)
        lossPart[blockIdx.x] = wsum[0] + wsum[1] + wsum[2] + wsum[3];  // STORE, no atomic

    // coalesced z_q store
    {
        const int c = tid >> 2, u0 = (tid & 3) * 16;
        const float4* s4 = (const float4*)&z_s[c][u0];
        float4 f0 = s4[0], f1 = s4[1], f2 = s4[2], f3 = s4[3];
        float* dst = zq + (size_t)b * B_STRIDE + (size_t)c * CH_STRIDE + hw0 + u0;
        *(float4*)(dst) = f0;
        *(float4*)(dst + 4) = f1;
        *(float4*)(dst + 8) = f2;
        *(float4*)(dst + 12) = f3;
    }
}

__global__ __launch_bounds__(256) void vq_final(const int* __restrict__ hist,
                                                const double* __restrict__ lossPart,
                                                float* __restrict__ outs) {
    __shared__ double red[256];
    __shared__ double red2[256];
    double acc = 0.0;
    for (int j = threadIdx.x; j < NE; j += 256) {
        double em = (double)hist[j] * (1.0 / 65536.0);
        acc += em * log(em + 1e-10);
    }
    double lsum = 0.0;
    for (int j = threadIdx.x; j < 1024; j += 256) lsum += lossPart[j];
    red[threadIdx.x] = acc;
    red2[threadIdx.x] = lsum;
    __syncthreads();
    for (int s = 128; s > 0; s >>= 1) {
        if (threadIdx.x < s) {
            red[threadIdx.x] += red[threadIdx.x + s];
            red2[threadIdx.x] += red2[threadIdx.x + s];
        }
        __syncthreads();
    }
    if (threadIdx.x == 0) {
        outs[0] = (float)(1.25 * red2[0] * (1.0 / 4194304.0));
        outs[1] = (float)exp(-red[0]);
    }
}

extern "C" void kernel_launch(void* const* d_in, const int* in_sizes, int n_in,
                              void* d_out, int out_size, void* d_ws, size_t ws_size,
                              hipStream_t stream) {
    const float* z = (const float*)d_in[0];
    const float* emb = (const float*)d_in[1];
    float* out = (float*)d_out;

    char* ws = (char*)d_ws;
    ushort_t* efrag = (ushort_t*)ws;
    float* enorm = (float*)(ws + 131072);
    int* hist = (int*)(ws + 135168);
    double* lossPart = (double*)(ws + 143360);

    float* zq = out;                        // [0, 4194304)
    float* scalars = out + 4194304;         // loss, perplexity
    float* out_idx = out + 4194306;         // 65536 indices as float

    vq_prep_e<<<256, 256, 0, stream>>>(emb, efrag, enorm, hist);
    vq_main<<<1024, 256, 0, stream>>>(z, efrag, enorm, emb, zq, out_idx, hist, lossPart);
    vq_final<<<1, 256, 0, stream>>>(hist, lossPart, scalars);
}

// Round 13
// 46.134 us; speedup vs baseline: 1.0385x; 1.0385x over previous
//
#include <hip/hip_runtime.h>

#define TOKS 65536
#define ED 64
#define NE 1024
#define CH_STRIDE 4096      // 64*64
#define B_STRIDE 262144     // 64*64*64

typedef __bf16 bf16x8 __attribute__((ext_vector_type(8)));
typedef float f32x16 __attribute__((ext_vector_type(16)));
typedef unsigned short ushort_t;
typedef unsigned int uint_t;

// ws layout:
//   efrag    @ 0      : 32ct x 4ks x 64lane x 8 bf16 (hi of -2*emb) [128 KB]
//   enorm    @ 131072 : 1024 f32 (np-pairwise ||e||^2, exact)        [4 KB]
//   hist     @ 135168 : 1024 i32                                     [4 KB]
//   lossPart @ 143360 : 1024 f64 per-block partial loss              [8 KB]

__device__ __forceinline__ ushort_t f2bf(float x) {
    uint_t u = __float_as_uint(x);
    uint_t r = u + 0x7FFFu + ((u >> 16) & 1u);   // RNE
    return (ushort_t)(r >> 16);
}

// ---- prep E: wave per code. enorm via shfl-replicated numpy pairwise (exact
// op order: 8 accumulators, 7 sequential stride-8 adds, 3-level tree).
__global__ __launch_bounds__(256) void vq_prep_e(const float* __restrict__ emb,
                                                 ushort_t* __restrict__ efrag,
                                                 float* __restrict__ enorm,
                                                 int* __restrict__ hist) {
    const int tid = threadIdx.x;
    const int w = tid >> 6, lane = tid & 63;
    const int j = blockIdx.x * 4 + w;

    const float e = emb[j * 64 + lane];
    const float sq = __fmul_rn(e, e);
    float acc = sq;
    acc = __fadd_rn(acc, __shfl_down(sq, 8, 64));
    acc = __fadd_rn(acc, __shfl_down(sq, 16, 64));
    acc = __fadd_rn(acc, __shfl_down(sq, 24, 64));
    acc = __fadd_rn(acc, __shfl_down(sq, 32, 64));
    acc = __fadd_rn(acc, __shfl_down(sq, 40, 64));
    acc = __fadd_rn(acc, __shfl_down(sq, 48, 64));
    acc = __fadd_rn(acc, __shfl_down(sq, 56, 64));
    float x = __fadd_rn(acc, __shfl_down(acc, 1, 64));
    float y = __fadd_rn(x, __shfl_down(x, 2, 64));
    float zn = __fadd_rn(y, __shfl_down(y, 4, 64));
    if (lane == 0) enorm[j] = zn;

    const ushort_t h = f2bf(-2.0f * e);
    const int ct = j >> 5, m = j & 31;
    const int ks = lane >> 4, kh = (lane >> 3) & 1, i = lane & 7;
    efrag[(size_t)((ct * 4 + ks) * 512) + (m + 32 * kh) * 8 + i] = h;

    if (blockIdx.x < 4) hist[blockIdx.x * 256 + tid] = 0;
}

// ---- fused: MFMA filter + compacted exact rescore + gather/hist/loss + zq.
// z tile TOKEN-MAJOR in LDS -> b128 reads; minimal VMEM instruction count.
__global__ __launch_bounds__(256, 4) void vq_main(
    const float* __restrict__ z,
    const ushort_t* __restrict__ efrag,
    const float* __restrict__ enorm,
    const float* __restrict__ emb,
    float* __restrict__ zq,
    float* __restrict__ out_idx,
    int* __restrict__ hist,
    double* __restrict__ lossPart) {
    __shared__ float z_s[64][72];                 // [token][channel], row 288B
    __shared__ uint_t skey[4][2][32][2][2];       // [wave][tile][n][kh][slot]
    __shared__ float s_zn[64];
    __shared__ unsigned long long s_res[64];      // lex-min (d_bits<<10 | j)
    __shared__ uint_t s_cand[256];                // (token<<10) | j
    __shared__ int s_cnt;
    __shared__ double wsum[4];

    const int tid = threadIdx.x;
    const int w = tid >> 6, lane = tid & 63;
    const int t0 = blockIdx.x * 64;
    const int b = t0 >> 12, hw0 = t0 & 4095;
    const float* zbase = z + (size_t)b * B_STRIDE + hw0;

    // stage z ONCE (4 float4 loads/thread) + transpose into token-major LDS
    {
        const int c = tid >> 2, u0 = (tid & 3) * 16;
        const float* src = zbase + (size_t)c * CH_STRIDE + u0;
        float4 f0 = *(const float4*)(src);
        float4 f1 = *(const float4*)(src + 4);
        float4 f2 = *(const float4*)(src + 8);
        float4 f3 = *(const float4*)(src + 12);
        z_s[u0 +  0][c] = f0.x; z_s[u0 +  1][c] = f0.y;
        z_s[u0 +  2][c] = f0.z; z_s[u0 +  3][c] = f0.w;
        z_s[u0 +  4][c] = f1.x; z_s[u0 +  5][c] = f1.y;
        z_s[u0 +  6][c] = f1.z; z_s[u0 +  7][c] = f1.w;
        z_s[u0 +  8][c] = f2.x; z_s[u0 +  9][c] = f2.y;
        z_s[u0 + 10][c] = f2.z; z_s[u0 + 11][c] = f2.w;
        z_s[u0 + 12][c] = f3.x; z_s[u0 + 13][c] = f3.y;
        z_s[u0 + 14][c] = f3.z; z_s[u0 + 15][c] = f3.w;
    }
    if (tid < 64) s_res[tid] = 0xFFFFFFFFFFFFFFFFull;
    if (tid == 0) s_cnt = 0;
    __syncthreads();

    const int n = lane & 31, kh = lane >> 5;

    // B-frags from LDS (b128 contiguous rows), tiles A (tok n) / B (tok 32+n)
    bf16x8 zbA[4], zbB[4];
    #pragma unroll
    for (int ks = 0; ks < 4; ++ks) {
        float4 a0 = *(const float4*)&z_s[n][ks * 16 + kh * 8];
        float4 a1 = *(const float4*)&z_s[n][ks * 16 + kh * 8 + 4];
        float4 b0 = *(const float4*)&z_s[32 + n][ks * 16 + kh * 8];
        float4 b1 = *(const float4*)&z_s[32 + n][ks * 16 + kh * 8 + 4];
        const float av[8] = {a0.x, a0.y, a0.z, a0.w, a1.x, a1.y, a1.z, a1.w};
        const float bv[8] = {b0.x, b0.y, b0.z, b0.w, b1.x, b1.y, b1.z, b1.w};
        #pragma unroll
        for (int i = 0; i < 8; ++i) {
            union { ushort_t u; __bf16 bh; } ca, cb;
            ca.u = f2bf(av[i]);
            cb.u = f2bf(bv[i]);
            zbA[ks][i] = ca.bh;
            zbB[ks][i] = cb.bh;
        }
    }

    uint_t kA0 = 0xFFFFFFFFu, kA1 = 0xFFFFFFFFu;
    uint_t kB0 = 0xFFFFFFFFu, kB1 = 0xFFFFFFFFu;
    const bf16x8* eg = (const bf16x8*)efrag;
    const int rot = blockIdx.x & 7;                // de-lockstep co-resident blocks

    // prologue: load fragments for first visited ct
    int gct = w * 8 + rot;
    bf16x8 ah0 = eg[(size_t)(gct * 4 + 0) * 64 + lane];
    bf16x8 ah1 = eg[(size_t)(gct * 4 + 1) * 64 + lane];
    bf16x8 ah2 = eg[(size_t)(gct * 4 + 2) * 64 + lane];
    bf16x8 ah3 = eg[(size_t)(gct * 4 + 3) * 64 + lane];

    for (int ct = 0; ct < 8; ++ct) {
        const int gnext = w * 8 + ((ct + 1 + rot) & 7);
        bf16x8 nx0, nx1, nx2, nx3;
        if (ct < 7) {                              // prefetch next ct
            nx0 = eg[(size_t)(gnext * 4 + 0) * 64 + lane];
            nx1 = eg[(size_t)(gnext * 4 + 1) * 64 + lane];
            nx2 = eg[(size_t)(gnext * 4 + 2) * 64 + lane];
            nx3 = eg[(size_t)(gnext * 4 + 3) * 64 + lane];
        }
        const int jb = gct * 32 + 4 * kh;

        f32x16 accA;
        #pragma unroll
        for (int r = 0; r < 16; ++r) accA[r] = 0.25f;
        accA = __builtin_amdgcn_mfma_f32_32x32x16_bf16(ah0, zbA[0], accA, 0, 0, 0);
        accA = __builtin_amdgcn_mfma_f32_32x32x16_bf16(ah1, zbA[1], accA, 0, 0, 0);
        accA = __builtin_amdgcn_mfma_f32_32x32x16_bf16(ah2, zbA[2], accA, 0, 0, 0);
        accA = __builtin_amdgcn_mfma_f32_32x32x16_bf16(ah3, zbA[3], accA, 0, 0, 0);

        f32x16 accB;
        #pragma unroll
        for (int r = 0; r < 16; ++r) accB[r] = 0.25f;
        accB = __builtin_amdgcn_mfma_f32_32x32x16_bf16(ah0, zbB[0], accB, 0, 0, 0);
        accB = __builtin_amdgcn_mfma_f32_32x32x16_bf16(ah1, zbB[1], accB, 0, 0, 0);
        accB = __builtin_amdgcn_mfma_f32_32x32x16_bf16(ah2, zbB[2], accB, 0, 0, 0);
        accB = __builtin_amdgcn_mfma_f32_32x32x16_bf16(ah3, zbB[3], accB, 0, 0, 0);

        #pragma unroll
        for (int r = 0; r < 16; ++r) {
            const uint_t jbits = (uint_t)(jb + (r & 3) + 8 * (r >> 2));
            uint_t keyA = (__float_as_uint(accA[r]) & 0xFFFFFC00u) | jbits;
            uint_t mxA = max(kA0, keyA);
            kA1 = min(kA1, mxA);
            kA0 = min(kA0, keyA);
            uint_t keyB = (__float_as_uint(accB[r]) & 0xFFFFFC00u) | jbits;
            uint_t mxB = max(kB0, keyB);
            kB1 = min(kB1, mxB);
            kB0 = min(kB0, keyB);
        }
        ah0 = nx0; ah1 = nx1; ah2 = nx2; ah3 = nx3;
        gct = gnext;
    }

    skey[w][0][n][kh][0] = kA0; skey[w][0][n][kh][1] = kA1;
    skey[w][1][n][kh][0] = kB0; skey[w][1][n][kh][1] = kB1;
    __syncthreads();

    // ---- threshold + candidate compaction + znorm (4 threads per token)
    const int t_loc = tid >> 2, m = tid & 3;
    const int tile = t_loc >> 5, nn = t_loc & 31;
    {
        uint_t ck[4];
        ck[0] = skey[m][tile][nn][0][0];
        ck[1] = skey[m][tile][nn][0][1];
        ck[2] = skey[m][tile][nn][1][0];
        ck[3] = skey[m][tile][nn][1][1];
        uint_t kmin = min(min(ck[0], ck[1]), min(ck[2], ck[3]));
        kmin = min(kmin, (uint_t)__shfl_xor((int)kmin, 1, 64));
        kmin = min(kmin, (uint_t)__shfl_xor((int)kmin, 2, 64));
        const float thr = __uint_as_float(kmin & 0xFFFFFC00u) + 4.0e-4f;
        #pragma unroll
        for (int s = 0; s < 4; ++s) {
            if (__uint_as_float(ck[s] & 0xFFFFFC00u) <= thr) {
                int pos = atomicAdd(&s_cnt, 1);
                if (pos < 256)
                    s_cand[pos] = ((uint_t)t_loc << 10) | (ck[s] & 1023u);
            }
        }
    }
    {   // znorm: np pairwise, exact op order; thread m owns slices m and m+4
        float a0 = z_s[t_loc][m];
        float ra = __fmul_rn(a0, a0);
        float b0 = z_s[t_loc][m + 4];
        float rb = __fmul_rn(b0, b0);
        #pragma unroll
        for (int i = 1; i < 8; ++i) {
            float av = z_s[t_loc][m + 8 * i];
            ra = __fadd_rn(ra, __fmul_rn(av, av));
            float bv = z_s[t_loc][m + 4 + 8 * i];
            rb = __fadd_rn(rb, __fmul_rn(bv, bv));
        }
        float xa = __fadd_rn(ra, __shfl_xor(ra, 1, 64));
        float A = __fadd_rn(xa, __shfl_xor(xa, 2, 64));
        float xb = __fadd_rn(rb, __shfl_xor(rb, 1, 64));
        float B = __fadd_rn(xb, __shfl_xor(xb, 2, 64));
        if (m == 0) s_zn[t_loc] = __fadd_rn(A, B);
    }
    __syncthreads();

    // ---- compacted exact rescore: one candidate per thread (b128 z reads)
    {
        const int cnt = s_cnt;
        if (tid < cnt && tid < 256) {
            const uint_t cd = s_cand[tid];
            const int tok = (int)(cd >> 10), j = (int)(cd & 1023u);
            const float* e = emb + (size_t)j * 64;
            float a0 = 0.f;
            #pragma unroll
            for (int k4 = 0; k4 < 16; ++k4) {
                float4 z4 = *(const float4*)&z_s[tok][k4 * 4];
                float4 e4 = *(const float4*)(e + k4 * 4);
                a0 = __fmaf_rn(z4.x, e4.x, a0);
                a0 = __fmaf_rn(z4.y, e4.y, a0);
                a0 = __fmaf_rn(z4.z, e4.z, a0);
                a0 = __fmaf_rn(z4.w, e4.w, a0);
            }
            float d = __fsub_rn(__fadd_rn(s_zn[tok], enorm[j]), 2.0f * a0);
            unsigned long long key =
                ((unsigned long long)__float_as_uint(d) << 10)
                | (unsigned long long)j;
            atomicMin(&s_res[tok], key);
        }
    }
    __syncthreads();

    // ---- gather + loss: 4 threads/token, each owns 16 contiguous channels
    const int bj = (int)(s_res[t_loc] & 1023u);
    if (m == 0) {
        out_idx[t0 + t_loc] = (float)bj;
        atomicAdd(&hist[bj], 1);
    }
    double ls = 0.0;
    {
        const float* e = emb + (size_t)bj * 64 + m * 16;
        float4 e0 = *(const float4*)(e);
        float4 e1 = *(const float4*)(e + 4);
        float4 e2 = *(const float4*)(e + 8);
        float4 e3 = *(const float4*)(e + 12);
        float4 zv0 = *(const float4*)&z_s[t_loc][m * 16];
        float4 zv1 = *(const float4*)&z_s[t_loc][m * 16 + 4];
        float4 zv2 = *(const float4*)&z_s[t_loc][m * 16 + 8];
        float4 zv3 = *(const float4*)&z_s[t_loc][m * 16 + 12];
        float df;
        df = e0.x - zv0.x; ls += (double)(df * df);
        df = e0.y - zv0.y; ls += (double)(df * df);
        df = e0.z - zv0.z; ls += (double)(df * df);
        df = e0.w - zv0.w; ls += (double)(df * df);
        df = e1.x - zv1.x; ls += (double)(df * df);
        df = e1.y - zv1.y; ls += (double)(df * df);
        df = e1.z - zv1.z; ls += (double)(df * df);
        df = e1.w - zv1.w; ls += (double)(df * df);
        df = e2.x - zv2.x; ls += (double)(df * df);
        df = e2.y - zv2.y; ls += (double)(df * df);
        df = e2.z - zv2.z; ls += (double)(df * df);
        df = e2.w - zv2.w; ls += (double)(df * df);
        df = e3.x - zv3.x; ls += (double)(df * df);
        df = e3.y - zv3.y; ls += (double)(df * df);
        df = e3.z - zv3.z; ls += (double)(df * df);
        df = e3.w - zv3.w; ls += (double)(df * df);
        *(float4*)&z_s[t_loc][m * 16] = e0;        // tile becomes z_q
        *(float4*)&z_s[t_loc][m * 16 + 4] = e1;
        *(float4*)&z_s[t_loc][m * 16 + 8] = e2;
        *(float4*)&z_s[t_loc][m * 16 + 12] = e3;
    }
    #pragma unroll
    for (int off = 32; off > 0; off >>= 1) ls += __shfl_down(ls, off, 64);
    if (lane == 0) wsum[w] = ls;
    __syncthreads();                               // z_s fully z_q; wsum ready
    if (tid == 0)
        lossPart[blockIdx.x] = wsum[0] + wsum[1] + wsum[2] + wsum[3];

    // coalesced z_q store (transpose back out of token-major LDS)
    {
        const int c = tid >> 2, u0 = (tid & 3) * 16;
        float4 f0, f1, f2, f3;
        f0.x = z_s[u0 +  0][c]; f0.y = z_s[u0 +  1][c];
        f0.z = z_s[u0 +  2][c]; f0.w = z_s[u0 +  3][c];
        f1.x = z_s[u0 +  4][c]; f1.y = z_s[u0 +  5][c];
        f1.z = z_s[u0 +  6][c]; f1.w = z_s[u0 +  7][c];
        f2.x = z_s[u0 +  8][c]; f2.y = z_s[u0 +  9][c];
        f2.z = z_s[u0 + 10][c]; f2.w = z_s[u0 + 11][c];
        f3.x = z_s[u0 + 12][c]; f3.y = z_s[u0 + 13][c];
        f3.z = z_s[u0 + 14][c]; f3.w = z_s[u0 + 15][c];
        float* dst = zq + (size_t)b * B_STRIDE + (size_t)c * CH_STRIDE + hw0 + u0;
        *(float4*)(dst) = f0;
        *(float4*)(dst + 4) = f1;
        *(float4*)(dst + 8) = f2;
        *(float4*)(dst + 12) = f3;
    }
}

__global__ __launch_bounds__(256) void vq_final(const int* __restrict__ hist,
                                                const double* __restrict__ lossPart,
                                                float* __restrict__ outs) {
    __shared__ double red[256];
    __shared__ double red2[256];
    double acc = 0.0;
    for (int j = threadIdx.x; j < NE; j += 256) {
        double em = (double)hist[j] * (1.0 / 65536.0);
        acc += em * log(em + 1e-10);
    }
    double lsum = 0.0;
    for (int j = threadIdx.x; j < 1024; j += 256) lsum += lossPart[j];
    red[threadIdx.x] = acc;
    red2[threadIdx.x] = lsum;
    __syncthreads();
    for (int s = 128; s > 0; s >>= 1) {
        if (threadIdx.x < s) {
            red[threadIdx.x] += red[threadIdx.x + s];
            red2[threadIdx.x] += red2[threadIdx.x + s];
        }
        __syncthreads();
    }
    if (threadIdx.x == 0) {
        outs[0] = (float)(1.25 * red2[0] * (1.0 / 4194304.0));
        outs[1] = (float)exp(-red[0]);
    }
}

extern "C" void kernel_launch(void* const* d_in, const int* in_sizes, int n_in,
                              void* d_out, int out_size, void* d_ws, size_t ws_size,
                              hipStream_t stream) {
    const float* z = (const float*)d_in[0];
    const float* emb = (const float*)d_in[1];
    float* out = (float*)d_out;

    char* ws = (char*)d_ws;
    ushort_t* efrag = (ushort_t*)ws;
    float* enorm = (float*)(ws + 131072);
    int* hist = (int*)(ws + 135168);
    double* lossPart = (double*)(ws + 143360);

    float* zq = out;                        // [0, 4194304)
    float* scalars = out + 4194304;         // loss, perplexity
    float* out_idx = out + 4194306;         // 65536 indices as float

    vq_prep_e<<<256, 256, 0, stream>>>(emb, efrag, enorm, hist);
    vq_main<<<1024, 256, 0, stream>>>(z, efrag, enorm, emb, zq, out_idx, hist, lossPart);
    vq_final<<<1, 256, 0, stream>>>(hist, lossPart, scalars);
}